// Round 4
// baseline (620.512 us; speedup 1.0000x reference)
//
#include <hip/hip_runtime.h>
#include <math.h>
#include <stdint.h>

// Problem constants: BS=16, SEQ=1024, NV=512, DM=256, K=8
#define BS 16
#define SEQ 1024
#define NV 512
#define DM 256
#define NK 8

// ---------------------------------------------------------------------------
// Module-global scratch. Every launch fully overwrites before reading
// (stream-ordered producer->consumer), so graph replay is self-contained.
// ---------------------------------------------------------------------------
__device__ double g_WC[NK * SEQ];                          // 64 KB
__device__ double g_Bk[NK];                                // 64 B
__device__ __align__(16) float g_Wt[SEQ * DM];             // 1 MB  [s][d]
__device__ __align__(16) float g_zp[4 * BS * NV * DM];     // 33.5 MB [kblk][b][v][d]
__device__ double g_nn2[BS * NV];                          // 64 KB
__device__ double g_Dp[8 * BS * NV * NK];                  // 4 MB [sc][b][v][k]
__device__ unsigned char g_bits[BS * NV];                  // 8 KB

// ---------------------------------------------------------------------------
// Exact JAX threefry2x32 (20 rounds), key = PRNGKey(7) = (0, 7).
// ---------------------------------------------------------------------------
__device__ __forceinline__ void threefry2x32_key7(uint32_t x0, uint32_t x1,
                                                  uint32_t& o0, uint32_t& o1) {
    const uint32_t k0 = 0u, k1 = 7u;
    const uint32_t k2 = k0 ^ k1 ^ 0x1BD11BDAu;
    uint32_t v0 = x0 + k0, v1 = x1 + k1;
#define TF_ROUND(r) { v0 += v1; v1 = (v1 << (r)) | (v1 >> (32 - (r))); v1 ^= v0; }
    TF_ROUND(13) TF_ROUND(15) TF_ROUND(26) TF_ROUND(6)
    v0 += k1; v1 += k2 + 1u;
    TF_ROUND(17) TF_ROUND(29) TF_ROUND(16) TF_ROUND(24)
    v0 += k2; v1 += k0 + 2u;
    TF_ROUND(13) TF_ROUND(15) TF_ROUND(26) TF_ROUND(6)
    v0 += k0; v1 += k1 + 3u;
    TF_ROUND(17) TF_ROUND(29) TF_ROUND(16) TF_ROUND(24)
    v0 += k1; v1 += k2 + 4u;
    TF_ROUND(13) TF_ROUND(15) TF_ROUND(26) TF_ROUND(6)
    v0 += k2; v1 += k0 + 5u;
#undef TF_ROUND
    o0 = v0; o1 = v1;
}

__device__ __forceinline__ float bits_to_uniform(uint32_t b) {
    return __uint_as_float((b >> 9) | 0x3F800000u) - 1.0f;
}

// ---------------------------------------------------------------------------
// Merged W-transpose + prep (proven). 64 blocks.
// Blocks 0..31: g_Wt[s][d] = W[d][s] (64s x 128d LDS tiles, both coalesced).
// Blocks 32..63: WC, Bk in fp64 (identical FP order to original prep).
// ---------------------------------------------------------------------------
__global__ __launch_bounds__(256) void prep_merged_kernel(
        const float* __restrict__ W, const float* __restrict__ bias,
        const float* __restrict__ ce) {
    __shared__ float tile[64][132];
    __shared__ double red[256];
    __shared__ double cen[256];
    const int t = threadIdx.x;
    const int bid = blockIdx.x;

    if (bid < 32) {
        const int s0 = (bid & 15) * 64;
        const int d0 = (bid >> 4) * 128;
#pragma unroll
        for (int p = 0; p < 32; ++p) {
            int lin = p * 256 + t;
            int d = lin >> 6, s = lin & 63;          // read coalesced over s
            tile[s][d] = W[(size_t)(d0 + d) * SEQ + s0 + s];
        }
        __syncthreads();
#pragma unroll
        for (int p = 0; p < 32; ++p) {
            int lin = p * 256 + t;
            int s = lin >> 7, d = lin & 127;         // write coalesced over d
            g_Wt[(size_t)(s0 + s) * DM + d0 + d] = tile[s][d];
        }
        return;
    }

    const int pid = bid - 32;
    const int k = pid >> 2;
    const int schunk = pid & 3;

    double c = (double)ce[k * DM + t];
    red[t] = c * c;
    __syncthreads();
    for (int off = 128; off > 0; off >>= 1) {
        if (t < off) red[t] += red[t + off];
        __syncthreads();
    }
    double nc = fmax(sqrt(red[0]), 1e-12);
    cen[t] = c / nc;
    __syncthreads();
    red[t] = (double)bias[t] * cen[t];
    __syncthreads();
    for (int off = 128; off > 0; off >>= 1) {
        if (t < off) red[t] += red[t + off];
        __syncthreads();
    }
    if (t == 0 && schunk == 0) g_Bk[k] = red[0];

    const int s = schunk * 256 + t;
    double acc = 0.0;
#pragma unroll 8
    for (int d = 0; d < DM; ++d)
        acc += cen[d] * (double)W[(size_t)d * SEQ + s];
    g_WC[(size_t)k * SEQ + s] = acc;
}

// ---------------------------------------------------------------------------
// GEMM: round-3 geometry (64v x 256d block tile, 8v x 8d thread tile = 64 acc,
// kblk=4 cross-block K-split, grid 512 = 2 blocks/CU) + T14 async-STAGE
// split: chunk c+1's 10 global float4 loads are issued into registers BEFORE
// the MAC phase of chunk c and ds_written AFTER the post-MAC barrier, so
// global latency hides under the ~4500-cyc MAC phase instead of being
// serially exposed 8x per block. VGPR: 64 acc + 40 prefetch + 16 operands
// + addr ~ 150 <= 256 -> still 2 waves/SIMD, no spill (round-2's spill came
// from 128 acc + prefetch; acc is 64 here). No __launch_bounds__ min-waves
// cap: occupancy comes from LDS (42.5 KB -> 2 blocks/CU) not a VGPR clamp.
// FP order (s-ascending per 256-chunk) and g_zp layout identical to baseline.
// ---------------------------------------------------------------------------
#define KC 32
#define XS_LD 68            // 64 + 4
#define WST_LD 264          // 256 + 8

__global__ __launch_bounds__(256) void gemm_kernel(
        const float* __restrict__ x) {
    __shared__ __align__(16) float xs[KC * XS_LD];     // 8.7 KB
    __shared__ __align__(16) float wst[KC * WST_LD];   // 33.8 KB

    const int t = threadIdx.x;
    const int kblk = blockIdx.x;    // 0..3
    const int vblk = blockIdx.y;    // 0..7
    const int b    = blockIdx.z;    // 0..15
    const int v0 = vblk * 64;
    const float* xb = x + (size_t)b * SEQ * NV;

    const int tv8 = (t & 7) * 8;         // v offset (8 rows)
    const int grp = t >> 3;              // 0..31 -> d group of 8
    const int td8 = grp * 8;             // d offset

    float acc[8][8];
#pragma unroll
    for (int j = 0; j < 8; ++j)
#pragma unroll
        for (int i = 0; i < 8; ++i) acc[j][i] = 0.0f;

    float4 rx[2], rw[8];

#define LOADCHUNK(S0)                                                          \
    {                                                                          \
        _Pragma("unroll")                                                      \
        for (int j = 0; j < 2; ++j) {                                          \
            int lin = j * 256 + t;                                             \
            int sl = lin >> 4, c4 = (lin & 15) << 2;                           \
            rx[j] = *(const float4*)&xb[(size_t)((S0) + sl) * NV + v0 + c4];   \
        }                                                                      \
        _Pragma("unroll")                                                      \
        for (int j = 0; j < 8; ++j) {                                          \
            int lin = j * 256 + t;                                             \
            int sl = lin >> 6, c4 = (lin & 63) << 2;                           \
            rw[j] = *(const float4*)&g_Wt[(size_t)((S0) + sl) * DM + c4];      \
        }                                                                      \
    }

#define WRITECHUNK()                                                           \
    {                                                                          \
        _Pragma("unroll")                                                      \
        for (int j = 0; j < 2; ++j) {                                          \
            int lin = j * 256 + t;                                             \
            int sl = lin >> 4, c4 = (lin & 15) << 2;                           \
            *(float4*)&xs[sl * XS_LD + c4] = rx[j];                            \
        }                                                                      \
        _Pragma("unroll")                                                      \
        for (int j = 0; j < 8; ++j) {                                          \
            int lin = j * 256 + t;                                             \
            int sl = lin >> 6, c4 = (lin & 63) << 2;                           \
            *(float4*)&wst[sl * WST_LD + c4] = rw[j];                          \
        }                                                                      \
    }

    const int sbeg = kblk * 256;

    // Prologue: stage chunk 0.
    LOADCHUNK(sbeg)
    WRITECHUNK()
    __syncthreads();

    for (int c = 0; c < 8; ++c) {
        if (c < 7) LOADCHUNK(sbeg + (c + 1) * KC)   // in flight during MAC

        // MAC phase on the staged chunk (proven inner loop, FP order kept).
#pragma unroll
        for (int kk = 0; kk < KC; ++kk) {
            const float* xr = &xs[kk * XS_LD + tv8];
            const float* wr = &wst[kk * WST_LD + td8];
            float4 xv0 = *(const float4*)(xr);
            float4 xv1 = *(const float4*)(xr + 4);
            float4 wv0 = *(const float4*)(wr);
            float4 wv1 = *(const float4*)(wr + 4);
            float xv[8] = {xv0.x, xv0.y, xv0.z, xv0.w, xv1.x, xv1.y, xv1.z, xv1.w};
            float wv[8] = {wv0.x, wv0.y, wv0.z, wv0.w, wv1.x, wv1.y, wv1.z, wv1.w};
#pragma unroll
            for (int j = 0; j < 8; ++j)
#pragma unroll
                for (int i = 0; i < 8; ++i) acc[j][i] += xv[j] * wv[i];
        }

        __syncthreads();              // all waves done reading LDS(c)
        if (c < 7) {
            WRITECHUNK()              // loads long since arrived; no stall
            __syncthreads();          // LDS(c+1) ready
        }
    }
#undef LOADCHUNK
#undef WRITECHUNK

    // Epilogue: fp32 z-partials for this kblk (same layout as baseline).
#pragma unroll
    for (int j = 0; j < 8; ++j) {
        size_t base = (size_t)kblk * (BS * NV * DM) +
                      ((size_t)b * NV + v0 + tv8 + j) * DM + td8;
#pragma unroll
        for (int m = 0; m < 8; m += 4)
            *(float4*)&g_zp[base + m] =
                make_float4(acc[j][m], acc[j][m + 1], acc[j][m + 2], acc[j][m + 3]);
    }
}

// ---------------------------------------------------------------------------
// Combine (proven baseline): z = fp64 sum of 4 kblk partials + bias;
// nn2 = sum_d z^2. Grid (vg 32, b 16) = 512 blocks.
// ---------------------------------------------------------------------------
__global__ __launch_bounds__(256) void combine_kernel(
        const float* __restrict__ bias) {
    __shared__ double red[16][17];
    const int t = threadIdx.x;
    const int vg = blockIdx.x;   // 0..31
    const int b  = blockIdx.y;   // 0..15
    const int vl = t >> 4, dg = t & 15;
    const int v = vg * 16 + vl;

    const size_t bvbase = ((size_t)b * NV + v) * DM + dg * 16;
    double sq = 0.0;
#pragma unroll
    for (int m = 0; m < 16; m += 4) {
        float4 p0 = *(const float4*)&g_zp[(size_t)0 * (BS * NV * DM) + bvbase + m];
        float4 p1 = *(const float4*)&g_zp[(size_t)1 * (BS * NV * DM) + bvbase + m];
        float4 p2 = *(const float4*)&g_zp[(size_t)2 * (BS * NV * DM) + bvbase + m];
        float4 p3 = *(const float4*)&g_zp[(size_t)3 * (BS * NV * DM) + bvbase + m];
        float4 bb = *(const float4*)&bias[dg * 16 + m];
        double z0 = (double)p0.x + (double)p1.x + (double)p2.x + (double)p3.x + (double)bb.x;
        double z1 = (double)p0.y + (double)p1.y + (double)p2.y + (double)p3.y + (double)bb.y;
        double z2 = (double)p0.z + (double)p1.z + (double)p2.z + (double)p3.z + (double)bb.z;
        double z3 = (double)p0.w + (double)p1.w + (double)p2.w + (double)p3.w + (double)bb.w;
        sq += z0 * z0 + z1 * z1 + z2 * z2 + z3 * z3;
    }
    red[vl][dg] = sq;
    __syncthreads();
    if (dg == 0) {
        double s = 0.0;
#pragma unroll
        for (int i = 0; i < 16; ++i) s += red[vl][i];
        g_nn2[b * NV + v] = s;
    }
}

// ---------------------------------------------------------------------------
// D-kernel (proven baseline): D_k partials over 128-s chunks, fp64.
// Grid: (vblk=8, b=16, sc=8) = 1024 blocks.
// ---------------------------------------------------------------------------
__global__ __launch_bounds__(256) void dkern(const float* __restrict__ x) {
    __shared__ double wcd[NK][128];
    __shared__ double dw[4][64][NK];
    const int t = threadIdx.x;
    const int vblk = blockIdx.x;
    const int b    = blockIdx.y;
    const int sc   = blockIdx.z;
    const int v0 = vblk * 64;
    const int ss = sc * 128;

#pragma unroll
    for (int j = 0; j < 4; ++j) {
        int idx = j * 256 + t;
        ((double*)wcd)[idx] = g_WC[(size_t)(idx >> 7) * SEQ + ss + (idx & 127)];
    }
    __syncthreads();

    const int vl = t & 63, w = t >> 6;
    const float* xp = x + (size_t)b * SEQ * NV + v0 + vl;
    double D[NK];
#pragma unroll
    for (int k = 0; k < NK; ++k) D[k] = 0.0;
    const int sw = w * 32;
    for (int i = 0; i < 32; ++i) {
        int sl = sw + i;
        double xv = (double)xp[(size_t)(ss + sl) * NV];
#pragma unroll
        for (int k = 0; k < NK; ++k) D[k] += xv * wcd[k][sl];
    }
#pragma unroll
    for (int k = 0; k < NK; ++k) dw[w][vl][k] = D[k];
    __syncthreads();

    const int v = t & 63, k2 = (t >> 6) * 2;
#pragma unroll
    for (int j = 0; j < 2; ++j) {
        int k = k2 + j;
        double s = dw[0][v][k] + dw[1][v][k] + dw[2][v][k] + dw[3][v][k];
        g_Dp[(((size_t)sc * BS + b) * NV + v0 + v) * NK + k] = s;
    }
}

// ---------------------------------------------------------------------------
// Finalize (unchanged): sinkhorn softmax fp64, partitionable threefry, bits.
// ---------------------------------------------------------------------------
__global__ __launch_bounds__(256) void finalize_kernel() {
    const int bv = blockIdx.x * 256 + threadIdx.x;   // 0..8191
    double n = fmax(sqrt(g_nn2[bv]), 1e-12);

    double D[NK];
#pragma unroll
    for (int k = 0; k < NK; ++k) D[k] = g_Bk[k];
#pragma unroll
    for (int sc = 0; sc < 8; ++sc) {
#pragma unroll
        for (int k = 0; k < NK; ++k)
            D[k] += g_Dp[((size_t)sc * (BS * NV) + bv) * NK + k];
    }

    double p[NK], sum = 0.0;
#pragma unroll
    for (int k = 0; k < NK; ++k) {
        p[k] = exp((D[k] / n) / 0.05);
        sum += p[k];
    }
    unsigned int byte = 0;
#pragma unroll
    for (int k = 0; k < NK; ++k) {
        uint32_t i = (uint32_t)(k * (BS * NV) + bv);
        uint32_t y0, y1;
        threefry2x32_key7(0u, i, y0, y1);
        float u = bits_to_uniform(y0 ^ y1);
        if ((double)u < p[k] / sum) byte |= 1u << k;
    }
    g_bits[bv] = (unsigned char)byte;
}

// ---------------------------------------------------------------------------
// Write (unchanged): 268 MB broadcast, float4 stores — at HBM floor.
// ---------------------------------------------------------------------------
__global__ __launch_bounds__(256) void write_kernel(float* __restrict__ out) {
    const int t = threadIdx.x;
    const size_t r0 = (size_t)blockIdx.x * 8;
#pragma unroll
    for (int j = 0; j < 8; ++j) {
        size_t r = r0 + j;                      // r = (k*16+b)*512+v
        unsigned int bv = (unsigned int)(r & 8191u);
        unsigned int k  = (unsigned int)(r >> 13);
        float v = ((g_bits[bv] >> k) & 1u) ? 1.0f : 0.0f;
        float4 val = make_float4(v, v, v, v);
        ((float4*)(out + r * 1024))[t] = val;
    }
}

// ---------------------------------------------------------------------------
extern "C" void kernel_launch(void* const* d_in, const int* in_sizes, int n_in,
                              void* d_out, int out_size, void* d_ws, size_t ws_size,
                              hipStream_t stream) {
    const float* x    = (const float*)d_in[0];
    const float* W    = (const float*)d_in[1];
    const float* bias = (const float*)d_in[2];
    const float* ce   = (const float*)d_in[3];
    float* out = (float*)d_out;

    prep_merged_kernel<<<dim3(64), dim3(256), 0, stream>>>(W, bias, ce);
    gemm_kernel<<<dim3(4, 8, 16), dim3(256), 0, stream>>>(x);
    combine_kernel<<<dim3(32, 16), dim3(256), 0, stream>>>(bias);
    dkern<<<dim3(8, 16, 8), dim3(256), 0, stream>>>(x);
    finalize_kernel<<<dim3(32), dim3(256), 0, stream>>>();
    write_kernel<<<dim3(8192), dim3(256), 0, stream>>>(out);
}

// Round 5
// 387.010 us; speedup vs baseline: 1.6033x; 1.6033x over previous
//
#include <hip/hip_runtime.h>
#include <math.h>
#include <stdint.h>

// Problem constants: BS=16, SEQ=1024, NV=512, DM=256, K=8
#define BS 16
#define SEQ 1024
#define NV 512
#define DM 256
#define NK 8

// ---------------------------------------------------------------------------
// Module-global scratch. Every launch fully overwrites before reading
// (stream-ordered producer->consumer), so graph replay is self-contained.
// ---------------------------------------------------------------------------
__device__ double g_WC[NK * SEQ];                          // 64 KB
__device__ double g_Bk[NK];                                // 64 B
__device__ __align__(16) float g_Wt[SEQ * DM];             // 1 MB  [s][d]
__device__ __align__(16) float g_zp[4 * BS * NV * DM];     // 33.5 MB [kblk][b][v][d]
__device__ double g_nn2[BS * NV];                          // 64 KB
__device__ double g_Dp[8 * BS * NV * NK];                  // 4 MB [sc][b][v][k]
__device__ unsigned char g_bits[BS * NV];                  // 8 KB

// ---------------------------------------------------------------------------
// Exact JAX threefry2x32 (20 rounds), key = PRNGKey(7) = (0, 7).
// ---------------------------------------------------------------------------
__device__ __forceinline__ void threefry2x32_key7(uint32_t x0, uint32_t x1,
                                                  uint32_t& o0, uint32_t& o1) {
    const uint32_t k0 = 0u, k1 = 7u;
    const uint32_t k2 = k0 ^ k1 ^ 0x1BD11BDAu;
    uint32_t v0 = x0 + k0, v1 = x1 + k1;
#define TF_ROUND(r) { v0 += v1; v1 = (v1 << (r)) | (v1 >> (32 - (r))); v1 ^= v0; }
    TF_ROUND(13) TF_ROUND(15) TF_ROUND(26) TF_ROUND(6)
    v0 += k1; v1 += k2 + 1u;
    TF_ROUND(17) TF_ROUND(29) TF_ROUND(16) TF_ROUND(24)
    v0 += k2; v1 += k0 + 2u;
    TF_ROUND(13) TF_ROUND(15) TF_ROUND(26) TF_ROUND(6)
    v0 += k0; v1 += k1 + 3u;
    TF_ROUND(17) TF_ROUND(29) TF_ROUND(16) TF_ROUND(24)
    v0 += k1; v1 += k2 + 4u;
    TF_ROUND(13) TF_ROUND(15) TF_ROUND(26) TF_ROUND(6)
    v0 += k2; v1 += k0 + 5u;
#undef TF_ROUND
    o0 = v0; o1 = v1;
}

__device__ __forceinline__ float bits_to_uniform(uint32_t b) {
    return __uint_as_float((b >> 9) | 0x3F800000u) - 1.0f;
}

// ---------------------------------------------------------------------------
// Async global->LDS 16B copy (zero VGPR staging; the compiler never emits
// this on its own). LDS dest is wave-uniform base + lane*16; global src is
// per-lane. Drained by the vmcnt(0) the compiler emits before s_barrier.
// ---------------------------------------------------------------------------
__device__ __forceinline__ void cp16(const float* g, float* l) {
    __builtin_amdgcn_global_load_lds(
        (const __attribute__((address_space(1))) void*)g,
        (__attribute__((address_space(3))) void*)l,
        16, 0, 0);
}

// ---------------------------------------------------------------------------
// Merged W-transpose + prep (proven). 64 blocks.
// Blocks 0..31: g_Wt[s][d] = W[d][s] (64s x 128d LDS tiles, both coalesced).
// Blocks 32..63: WC, Bk in fp64 (identical FP order to original prep).
// ---------------------------------------------------------------------------
__global__ __launch_bounds__(256) void prep_merged_kernel(
        const float* __restrict__ W, const float* __restrict__ bias,
        const float* __restrict__ ce) {
    __shared__ float tile[64][132];
    __shared__ double red[256];
    __shared__ double cen[256];
    const int t = threadIdx.x;
    const int bid = blockIdx.x;

    if (bid < 32) {
        const int s0 = (bid & 15) * 64;
        const int d0 = (bid >> 4) * 128;
#pragma unroll
        for (int p = 0; p < 32; ++p) {
            int lin = p * 256 + t;
            int d = lin >> 6, s = lin & 63;          // read coalesced over s
            tile[s][d] = W[(size_t)(d0 + d) * SEQ + s0 + s];
        }
        __syncthreads();
#pragma unroll
        for (int p = 0; p < 32; ++p) {
            int lin = p * 256 + t;
            int s = lin >> 7, d = lin & 127;         // write coalesced over d
            g_Wt[(size_t)(s0 + s) * DM + d0 + d] = tile[s][d];
        }
        return;
    }

    const int pid = bid - 32;
    const int k = pid >> 2;
    const int schunk = pid & 3;

    double c = (double)ce[k * DM + t];
    red[t] = c * c;
    __syncthreads();
    for (int off = 128; off > 0; off >>= 1) {
        if (t < off) red[t] += red[t + off];
        __syncthreads();
    }
    double nc = fmax(sqrt(red[0]), 1e-12);
    cen[t] = c / nc;
    __syncthreads();
    red[t] = (double)bias[t] * cen[t];
    __syncthreads();
    for (int off = 128; off > 0; off >>= 1) {
        if (t < off) red[t] += red[t + off];
        __syncthreads();
    }
    if (t == 0 && schunk == 0) g_Bk[k] = red[0];

    const int s = schunk * 256 + t;
    double acc = 0.0;
#pragma unroll 8
    for (int d = 0; d < DM; ++d)
        acc += cen[d] * (double)W[(size_t)d * SEQ + s];
    g_WC[(size_t)k * SEQ + s] = acc;
}

// ---------------------------------------------------------------------------
// GEMM: round-3 geometry (64v x 256d block tile, 8v x 8d thread tile = 64
// acc, kblk=4 cross-block K-split, grid 512 = 2 blocks/CU) with T3 2-phase
// async pipeline via global_load_lds (ZERO staging VGPRs -- the reg-prefetch
// variants of rounds 2/4 both spilled at VGPR=256; this is the fix):
//   loop: { DMA chunk c+1 -> LDS[buf^1]; MAC on LDS[buf]; __syncthreads(); }
// The DMA flies across the whole ~2000-cyc MAC phase; the barrier's
// compiler-emitted vmcnt(0) drain is residual-only. KC=16 double-buffered:
// LDS = 2*(16*64 + 16*256)*4 = 40 KB -> 2 blocks/CU with margin.
// Layouts unpadded (gload_lds writes linear lane-order): MAC reads hit
// banks {0,8,16,24} = 2-way aliasing = free. FP order is a single running
// acc over ascending s -> identical to baseline; g_zp layout unchanged.
// ---------------------------------------------------------------------------
#define KC 16

__global__ __launch_bounds__(256) void gemm_kernel(
        const float* __restrict__ x) {
    __shared__ __align__(16) float xs[2][KC * 64];      // 2 x 4 KB
    __shared__ __align__(16) float wst[2][KC * 256];    // 2 x 16 KB

    const int t = threadIdx.x;
    const int kblk = blockIdx.x;    // 0..3
    const int vblk = blockIdx.y;    // 0..7
    const int b    = blockIdx.z;    // 0..15
    const int v0 = vblk * 64;
    const float* xb = x + (size_t)b * SEQ * NV + v0;

    const int tv8 = (t & 7) * 8;         // v offset (8 rows)
    const int td8 = (t >> 3) * 8;        // d offset (32 groups of 8)
    const int w = t >> 6;                // wave 0..3
    const int l = t & 63;                // lane

    // Per-lane DMA source offsets (lane-invariant parts precomputed).
    const int wrow0 = w * 4;                      // this wave's first Wt row
    const size_t g_w_lane = (size_t)l * 4;        // lane offset into a Wt row
    const int xrow_sub = l >> 4;                  // x: lane's row within quad
    const int xcol = (l & 15) * 4;                // x: lane's col offset

    float acc[8][8];
#pragma unroll
    for (int j = 0; j < 8; ++j)
#pragma unroll
        for (int i = 0; i < 8; ++i) acc[j][i] = 0.0f;

#define STAGE(BUF, S0)                                                         \
    {                                                                          \
        _Pragma("unroll")                                                      \
        for (int j = 0; j < 4; ++j) {                                          \
            int row = wrow0 + j;                                               \
            cp16(&g_Wt[(size_t)((S0) + row) * DM + g_w_lane],                  \
                 &wst[BUF][row * 256]);                                        \
        }                                                                      \
        cp16(&xb[(size_t)((S0) + wrow0 + xrow_sub) * NV + xcol],               \
             &xs[BUF][wrow0 * 64]);                                            \
    }

    const int sbeg = kblk * 256;

    // Prologue: DMA chunk 0 into buf 0. Barrier drains vmcnt.
    STAGE(0, sbeg)
    __syncthreads();

    for (int c = 0; c < 16; ++c) {
        const int buf = c & 1;
        if (c < 15) STAGE(buf ^ 1, sbeg + (c + 1) * KC)   // async, in flight

        // MAC phase on the staged chunk (proven inner loop, FP order kept).
#pragma unroll
        for (int kk = 0; kk < KC; ++kk) {
            const float* xr = &xs[buf][kk * 64 + tv8];
            const float* wr = &wst[buf][kk * 256 + td8];
            float4 xv0 = *(const float4*)(xr);
            float4 xv1 = *(const float4*)(xr + 4);
            float4 wv0 = *(const float4*)(wr);
            float4 wv1 = *(const float4*)(wr + 4);
            float xv[8] = {xv0.x, xv0.y, xv0.z, xv0.w, xv1.x, xv1.y, xv1.z, xv1.w};
            float wv[8] = {wv0.x, wv0.y, wv0.z, wv0.w, wv1.x, wv1.y, wv1.z, wv1.w};
#pragma unroll
            for (int j = 0; j < 8; ++j)
#pragma unroll
                for (int i = 0; i < 8; ++i) acc[j][i] += xv[j] * wv[i];
        }

        __syncthreads();   // drains this iter's DMA + all waves done reading
    }
#undef STAGE

    // Epilogue: fp32 z-partials for this kblk (same layout as baseline).
#pragma unroll
    for (int j = 0; j < 8; ++j) {
        size_t base = (size_t)kblk * (BS * NV * DM) +
                      ((size_t)b * NV + v0 + tv8 + j) * DM + td8;
#pragma unroll
        for (int m = 0; m < 8; m += 4)
            *(float4*)&g_zp[base + m] =
                make_float4(acc[j][m], acc[j][m + 1], acc[j][m + 2], acc[j][m + 3]);
    }
}

// ---------------------------------------------------------------------------
// Combine (proven baseline): z = fp64 sum of 4 kblk partials + bias;
// nn2 = sum_d z^2. Grid (vg 32, b 16) = 512 blocks.
// ---------------------------------------------------------------------------
__global__ __launch_bounds__(256) void combine_kernel(
        const float* __restrict__ bias) {
    __shared__ double red[16][17];
    const int t = threadIdx.x;
    const int vg = blockIdx.x;   // 0..31
    const int b  = blockIdx.y;   // 0..15
    const int vl = t >> 4, dg = t & 15;
    const int v = vg * 16 + vl;

    const size_t bvbase = ((size_t)b * NV + v) * DM + dg * 16;
    double sq = 0.0;
#pragma unroll
    for (int m = 0; m < 16; m += 4) {
        float4 p0 = *(const float4*)&g_zp[(size_t)0 * (BS * NV * DM) + bvbase + m];
        float4 p1 = *(const float4*)&g_zp[(size_t)1 * (BS * NV * DM) + bvbase + m];
        float4 p2 = *(const float4*)&g_zp[(size_t)2 * (BS * NV * DM) + bvbase + m];
        float4 p3 = *(const float4*)&g_zp[(size_t)3 * (BS * NV * DM) + bvbase + m];
        float4 bb = *(const float4*)&bias[dg * 16 + m];
        double z0 = (double)p0.x + (double)p1.x + (double)p2.x + (double)p3.x + (double)bb.x;
        double z1 = (double)p0.y + (double)p1.y + (double)p2.y + (double)p3.y + (double)bb.y;
        double z2 = (double)p0.z + (double)p1.z + (double)p2.z + (double)p3.z + (double)bb.z;
        double z3 = (double)p0.w + (double)p1.w + (double)p2.w + (double)p3.w + (double)bb.w;
        sq += z0 * z0 + z1 * z1 + z2 * z2 + z3 * z3;
    }
    red[vl][dg] = sq;
    __syncthreads();
    if (dg == 0) {
        double s = 0.0;
#pragma unroll
        for (int i = 0; i < 16; ++i) s += red[vl][i];
        g_nn2[b * NV + v] = s;
    }
}

// ---------------------------------------------------------------------------
// D-kernel (proven baseline): D_k partials over 128-s chunks, fp64.
// Grid: (vblk=8, b=16, sc=8) = 1024 blocks.
// ---------------------------------------------------------------------------
__global__ __launch_bounds__(256) void dkern(const float* __restrict__ x) {
    __shared__ double wcd[NK][128];
    __shared__ double dw[4][64][NK];
    const int t = threadIdx.x;
    const int vblk = blockIdx.x;
    const int b    = blockIdx.y;
    const int sc   = blockIdx.z;
    const int v0 = vblk * 64;
    const int ss = sc * 128;

#pragma unroll
    for (int j = 0; j < 4; ++j) {
        int idx = j * 256 + t;
        ((double*)wcd)[idx] = g_WC[(size_t)(idx >> 7) * SEQ + ss + (idx & 127)];
    }
    __syncthreads();

    const int vl = t & 63, w = t >> 6;
    const float* xp = x + (size_t)b * SEQ * NV + v0 + vl;
    double D[NK];
#pragma unroll
    for (int k = 0; k < NK; ++k) D[k] = 0.0;
    const int sw = w * 32;
    for (int i = 0; i < 32; ++i) {
        int sl = sw + i;
        double xv = (double)xp[(size_t)(ss + sl) * NV];
#pragma unroll
        for (int k = 0; k < NK; ++k) D[k] += xv * wcd[k][sl];
    }
#pragma unroll
    for (int k = 0; k < NK; ++k) dw[w][vl][k] = D[k];
    __syncthreads();

    const int v = t & 63, k2 = (t >> 6) * 2;
#pragma unroll
    for (int j = 0; j < 2; ++j) {
        int k = k2 + j;
        double s = dw[0][v][k] + dw[1][v][k] + dw[2][v][k] + dw[3][v][k];
        g_Dp[(((size_t)sc * BS + b) * NV + v0 + v) * NK + k] = s;
    }
}

// ---------------------------------------------------------------------------
// Finalize (unchanged): sinkhorn softmax fp64, partitionable threefry, bits.
// ---------------------------------------------------------------------------
__global__ __launch_bounds__(256) void finalize_kernel() {
    const int bv = blockIdx.x * 256 + threadIdx.x;   // 0..8191
    double n = fmax(sqrt(g_nn2[bv]), 1e-12);

    double D[NK];
#pragma unroll
    for (int k = 0; k < NK; ++k) D[k] = g_Bk[k];
#pragma unroll
    for (int sc = 0; sc < 8; ++sc) {
#pragma unroll
        for (int k = 0; k < NK; ++k)
            D[k] += g_Dp[((size_t)sc * (BS * NV) + bv) * NK + k];
    }

    double p[NK], sum = 0.0;
#pragma unroll
    for (int k = 0; k < NK; ++k) {
        p[k] = exp((D[k] / n) / 0.05);
        sum += p[k];
    }
    unsigned int byte = 0;
#pragma unroll
    for (int k = 0; k < NK; ++k) {
        uint32_t i = (uint32_t)(k * (BS * NV) + bv);
        uint32_t y0, y1;
        threefry2x32_key7(0u, i, y0, y1);
        float u = bits_to_uniform(y0 ^ y1);
        if ((double)u < p[k] / sum) byte |= 1u << k;
    }
    g_bits[bv] = (unsigned char)byte;
}

// ---------------------------------------------------------------------------
// Write (unchanged): 268 MB broadcast, float4 stores — at HBM floor.
// ---------------------------------------------------------------------------
__global__ __launch_bounds__(256) void write_kernel(float* __restrict__ out) {
    const int t = threadIdx.x;
    const size_t r0 = (size_t)blockIdx.x * 8;
#pragma unroll
    for (int j = 0; j < 8; ++j) {
        size_t r = r0 + j;                      // r = (k*16+b)*512+v
        unsigned int bv = (unsigned int)(r & 8191u);
        unsigned int k  = (unsigned int)(r >> 13);
        float v = ((g_bits[bv] >> k) & 1u) ? 1.0f : 0.0f;
        float4 val = make_float4(v, v, v, v);
        ((float4*)(out + r * 1024))[t] = val;
    }
}

// ---------------------------------------------------------------------------
extern "C" void kernel_launch(void* const* d_in, const int* in_sizes, int n_in,
                              void* d_out, int out_size, void* d_ws, size_t ws_size,
                              hipStream_t stream) {
    const float* x    = (const float*)d_in[0];
    const float* W    = (const float*)d_in[1];
    const float* bias = (const float*)d_in[2];
    const float* ce   = (const float*)d_in[3];
    float* out = (float*)d_out;

    prep_merged_kernel<<<dim3(64), dim3(256), 0, stream>>>(W, bias, ce);
    gemm_kernel<<<dim3(4, 8, 16), dim3(256), 0, stream>>>(x);
    combine_kernel<<<dim3(32, 16), dim3(256), 0, stream>>>(bias);
    dkern<<<dim3(8, 16, 8), dim3(256), 0, stream>>>(x);
    finalize_kernel<<<dim3(32), dim3(256), 0, stream>>>();
    write_kernel<<<dim3(8192), dim3(256), 0, stream>>>(out);
}